// Round 2
// baseline (692.569 us; speedup 1.0000x reference)
//
#include <hip/hip_runtime.h>
#include <math.h>

// PixPro fused masked all-pairs cosine loss, MI355X (gfx950).
// B=2048, C=256, H=W=7 -> P=49 pixels.
// out[b] = -(1/2401) * sum_{p,q} wt[p][q] * dot(base_p, mom_q)/max(nb_p*nm_q, eps)
// where wt[p][q] = [base_A[p,q]==1] + [moment_A[q,p]==1]   (loss-term fusion).
//
// R2 structure: 1 batch per 128-thread block (2 waves), channel-split.
// Each wave owns 128 channels staged through wave-private LDS in 16-ch slabs
// with a padded pixel layout (slot = 8*(p/7)+p%7, channel stride 56) so the
// per-channel 7-pixel row reads are b128+b64+b32 instead of 7x b32.
// Final cross-wave reduction of 2401 partial dots + 98 partial norms via LDS.

constexpr int NB      = 2048;
constexpr int NC      = 256;
constexpr int NPIX    = 49;
constexpr int SLOTS   = 56;              // 7 rows * 8 (slot pad)
constexpr int SLAB_C  = 16;              // channels per slab
constexpr int HALF    = SLAB_C * SLOTS;  // 896 floats per feature (padded)
constexpr int SLABF   = SLAB_C * NPIX;   // 784 global floats per feature
constexpr int NS      = 8;               // slabs per wave (128 channels)
constexpr int WCH     = NS * SLAB_C;     // 128 channels per wave
constexpr float EPS   = 1e-6f;

// smem map (floats):
//   [0..1791]      wave0 staging (2*HALF)      } overwritten by acc regions
//   [1792..3583]   wave1 staging               } after the post-loop barrier
//   acc region w:  [w*2401 .. w*2401+2400]
//   nsq region w:  [4802 + w*98 .. +97]
constexpr int SMEM_FLOATS = 2 * 2401 + 2 * 98;  // 4998 -> 19992 B (<=20480 for 8 blk/CU)

__device__ __forceinline__ int slot_of(int p) { return ((p / 7) << 3) + (p % 7); }

__device__ __forceinline__ void scat4(float* st, int base, int r, float4 v) {
    // floats f..f+3 land at slot base, base+1+(r>=6), base+2+(r>=5), base+3+(r>=4)
    st[base]                = v.x;
    st[base + 1 + (r >= 6)] = v.y;
    st[base + 2 + (r >= 5)] = v.z;
    st[base + 3 + (r >= 4)] = v.w;
}

__global__ __launch_bounds__(128, 4)
void pixpro_kernel(const float* __restrict__ gbase,
                   const float* __restrict__ gmom,
                   const int*   __restrict__ A1,
                   const int*   __restrict__ A2,
                   float*       __restrict__ out)
{
    __shared__ __align__(16) float smem[SMEM_FLOATS];

    const int tid  = threadIdx.x;
    const int wave = tid >> 6;
    const int lane = tid & 63;
    const int b    = blockIdx.x;

    float* st = smem + wave * (2 * HALF);   // wave-private staging

    // lane (lp,lq) owns the 7x7 pair tile p=7lp.., q=7lq.. ; lp/lq==7 clamped+masked
    const int lp = lane & 7, lq = lane >> 3;
    const int lpc = (lp < 7 ? lp : 6), lqc = (lq < 7 ? lq : 6);
    const int p0 = lpc * 7, q0 = lqc * 7;

    const float* gb = gbase + (size_t)b * (NC * NPIX) + wave * (WCH * NPIX);
    const float* gm = gmom  + (size_t)b * (NC * NPIX) + wave * (WCH * NPIX);

    // staging-write offsets: chunk n covers global floats f..f+3, f = lane*4+n*256
    int wb[4], wr[4];
    {
        int f3 = 768 + ((lane < 4) ? lane * 4 : 12);
        int fs[4] = { lane * 4, lane * 4 + 256, lane * 4 + 512, f3 };
        #pragma unroll
        for (int n = 0; n < 4; ++n) {
            int f = fs[n], c = f / NPIX, p = f - c * NPIX;
            wb[n] = c * SLOTS + slot_of(p);
            wr[n] = p % 7;
        }
    }

    // norm accumulation assignment (per-wave partials over its 128 channels):
    //   nrm0: lane<49 -> base pixel lane ; lane>=49 -> mom pixel lane-49
    //   nrm1: lane<34 -> mom pixel 15+lane (clamped dummy otherwise)
    const float* vA = st + ((lane < NPIX) ? slot_of(lane) : HALF + slot_of(lane - NPIX));
    const float* vB = st + HALF + slot_of(lane < 34 ? 15 + lane : 48);
    const float* bp = st + 8 * lpc;
    const float* mp = st + HALF + 8 * lqc;

    float acc[7][7];
    #pragma unroll
    for (int j = 0; j < 7; ++j)
        #pragma unroll
        for (int i = 0; i < 7; ++i) acc[j][i] = 0.0f;
    float nrm0 = 0.0f, nrm1 = 0.0f;

    // prefetch slab 0
    float4 rb0, rb1, rb2, rb3 = {}, rm0, rm1, rm2, rm3 = {};
    {
        const float4* pb = (const float4*)gb;
        const float4* pm = (const float4*)gm;
        rb0 = pb[lane]; rb1 = pb[lane + 64]; rb2 = pb[lane + 128];
        rm0 = pm[lane]; rm1 = pm[lane + 64]; rm2 = pm[lane + 128];
        if (lane < 4) { rb3 = pb[lane + 192]; rm3 = pm[lane + 192]; }
    }

    for (int s = 0; s < NS; ++s) {
        // scatter current slab into padded LDS layout (wave-private, no barrier)
        scat4(st, wb[0], wr[0], rb0);  scat4(st + HALF, wb[0], wr[0], rm0);
        scat4(st, wb[1], wr[1], rb1);  scat4(st + HALF, wb[1], wr[1], rm1);
        scat4(st, wb[2], wr[2], rb2);  scat4(st + HALF, wb[2], wr[2], rm2);
        if (lane < 4) { scat4(st, wb[3], wr[3], rb3); scat4(st + HALF, wb[3], wr[3], rm3); }

        // prefetch next slab (hidden behind compute)
        if (s + 1 < NS) {
            const float4* pb = (const float4*)(gb + (s + 1) * SLABF);
            const float4* pm = (const float4*)(gm + (s + 1) * SLABF);
            rb0 = pb[lane]; rb1 = pb[lane + 64]; rb2 = pb[lane + 128];
            rm0 = pm[lane]; rm1 = pm[lane + 64]; rm2 = pm[lane + 128];
            if (lane < 4) { rb3 = pb[lane + 192]; rm3 = pm[lane + 192]; }
        }

        #pragma unroll
        for (int c = 0; c < SLAB_C; ++c) {
            const float* bc = bp + c * SLOTS;
            const float* mc = mp + c * SLOTS;
            float4 b03 = *(const float4*)bc;
            float2 b45 = *(const float2*)(bc + 4);
            float  b6  = bc[6];
            float4 m03 = *(const float4*)mc;
            float2 m45 = *(const float2*)(mc + 4);
            float  m6  = mc[6];
            float bv[7] = { b03.x, b03.y, b03.z, b03.w, b45.x, b45.y, b6 };
            float mv[7] = { m03.x, m03.y, m03.z, m03.w, m45.x, m45.y, m6 };
            float v0 = vA[c * SLOTS];
            float v1 = vB[c * SLOTS];
            nrm0 = fmaf(v0, v0, nrm0);
            nrm1 = fmaf(v1, v1, nrm1);
            #pragma unroll
            for (int j = 0; j < 7; ++j)
                #pragma unroll
                for (int i = 0; i < 7; ++i)
                    acc[j][i] = fmaf(bv[i], mv[j], acc[j][i]);
        }
    }

    // ---- cross-wave reduction ----
    __syncthreads();  // both waves done with staging before acc regions reuse it

    float* nsqw = smem + 2 * 2401 + wave * 98;
    nsqw[lane] = nrm0;                       // base 0..48 at [0..48], mom 0..14 at [49..63]
    if (lane < 34) nsqw[64 + lane] = nrm1;   // mom 15..48 at [64..97]

    float* accw = smem + wave * 2401;
    if (lp < 7 && lq < 7) {
        #pragma unroll
        for (int j = 0; j < 7; ++j)
            #pragma unroll
            for (int i = 0; i < 7; ++i)
                accw[(p0 + i) * NPIX + (q0 + j)] = acc[j][i];
    }
    __syncthreads();

    const float* acco = smem + (1 - wave) * 2401;
    const float* nsq0 = smem + 2 * 2401;
    const float* nsq1 = nsq0 + 98;

    float nbv[7], nmv[7];
    #pragma unroll
    for (int i = 0; i < 7; ++i) nbv[i] = sqrtf(nsq0[p0 + i] + nsq1[p0 + i]);
    #pragma unroll
    for (int j = 0; j < 7; ++j) nmv[j] = sqrtf(nsq0[NPIX + q0 + j] + nsq1[NPIX + q0 + j]);

    float sum = 0.0f;
    if (lp < 7 && lq < 7) {
        #pragma unroll
        for (int j = 0; j < 7; ++j) {
            #pragma unroll
            for (int i = 0; i < 7; ++i) {
                int pi = p0 + i, qj = q0 + j;
                float d = acc[j][i] + acco[pi * NPIX + qj];
                float w = (A1[pi * NPIX + qj] == 1 ? 1.0f : 0.0f)
                        + (A2[qj * NPIX + pi] == 1 ? 1.0f : 0.0f);
                sum += w * d / fmaxf(nbv[i] * nmv[j], EPS);
            }
        }
    }

    // 64-lane butterfly; both waves hold the full sum, wave0 lane0 stores
    #pragma unroll
    for (int m = 32; m; m >>= 1) sum += __shfl_xor(sum, m, 64);

    if (tid == 0) out[b] = sum * (-1.0f / 2401.0f);
}

extern "C" void kernel_launch(void* const* d_in, const int* in_sizes, int n_in,
                              void* d_out, int out_size, void* d_ws, size_t ws_size,
                              hipStream_t stream)
{
    (void)in_sizes; (void)n_in; (void)d_ws; (void)ws_size; (void)out_size;
    const float* base = (const float*)d_in[0];
    const float* mom  = (const float*)d_in[1];
    const int*   A1   = (const int*)d_in[2];
    const int*   A2   = (const int*)d_in[3];
    float*       out  = (float*)d_out;

    pixpro_kernel<<<NB, 128, 0, stream>>>(base, mom, A1, A2, out);
}

// Round 3
// 350.748 us; speedup vs baseline: 1.9745x; 1.9745x over previous
//
#include <hip/hip_runtime.h>
#include <math.h>

// PixPro fused masked all-pairs cosine loss, MI355X (gfx950).
// B=2048, C=256, H=W=7 -> P=49 pixels.
// out[b] = -(1/2401) * sum_{p,q} wt[p][q] * dot(base_p, mom_q)/max(nb_p*nm_q, eps)
// wt[p][q] = [base_A[p,q]==1] + [moment_A[q,p]==1]   (loss-term fusion).
//
// R3: NO LDS in the main loop. One batch per 256-thread block; wave w handles
// channels c ≡ w (mod 4). Lane grid 8x8, each main lane owns an 8x8 (p,q)
// register tile fed by 4 aligned global_load_dwordx4 per channel (8 lanes
// share each address -> HW broadcast; L1/L2 serve the reuse). Alignment of
// 49c+p0 is guaranteed by per-wave tile shift s=(4-r)&3. Waste lanes
// (lp==7 / lq==7) load the same tile into both operands so their accumulator
// diagonal is the squared pixel norm (free). Cross-wave combine via LDS
// f32 atomics (epilogue only), then a 2401-cell cosine pass + block reduce.

constexpr int NBATCH = 2048;
constexpr int NC     = 256;
constexpr int NP     = 49;
constexpr int FPB    = NC * NP;   // 12544 floats per feature per batch
constexpr float EPS  = 1e-6f;

__device__ __forceinline__ int tile_start(int g, int s) {
    // tiles for groups 0..5: 8g+s ; group 6 covers the leftover:
    //   s==0 -> 48 (reads 48..55, in-row-overrun is in-bounds garbage)
    //   s>0  -> s-4 (covers pixels 0..s-1; negative part is in-bounds garbage
    //               since these waves start at channel r>=1)
    if (g < 6) return 8 * g + s;
    return (s > 0) ? (s - 4) : 48;
}

__device__ __forceinline__ void own_range(int g, int s, int& lo, int& hi) {
    // which i in [0,8) of the tile this group OWNS (covers each p in 0..48
    // exactly once across groups)
    if (g < 6) { lo = 0; int h = 49 - (8 * g + s); hi = (h > 8) ? 8 : h; }
    else if (s > 0) { lo = 4 - s; hi = 4; }   // owns p = 0..s-1
    else { lo = 0; hi = 1; }                  // owns p = 48
}

__global__ __launch_bounds__(256)
void pixpro_kernel(const float* __restrict__ gbase,
                   const float* __restrict__ gmom,
                   const int*   __restrict__ A1,
                   const int*   __restrict__ A2,
                   float*       __restrict__ out)
{
    __shared__ float dots[NP * NP];   // combined dot partials
    __shared__ float bn[NP];          // sum base^2 per p
    __shared__ float mn[NP];          // sum mom^2  per q
    __shared__ float red[4];

    const int tid  = threadIdx.x;
    const int wave = tid >> 6;
    const int lane = tid & 63;
    const int b    = blockIdx.x;

    // zero LDS accumulators
    for (int t = tid; t < NP * NP; t += 256) dots[t] = 0.0f;
    if (tid < NP) { bn[tid] = 0.0f; mn[tid] = 0.0f; }
    __syncthreads();

    const int r = wave;            // channel residue this wave handles
    const int s = (4 - r) & 3;     // tile shift so 49c + tile ≡ 0 (mod 4)
    const int lp = lane & 7, lq = lane >> 3;

    const float* fb = gbase + (size_t)b * FPB;
    const float* fm = gmom  + (size_t)b * FPB;

    // operand pointer/tile selection per lane role
    const float* pA; const float* pB; int tA, tB;
    if (lp <= 6 && lq <= 6)      { pA = fb; tA = tile_start(lp, s); pB = fm; tB = tile_start(lq, s); }
    else if (lp == 7 && lq <= 6) { int t = tile_start(lq, s); pA = fb; pB = fb; tA = t; tB = t; }  // base-norm lane
    else if (lq == 7 && lp <= 6) { int t = tile_start(lp, s); pA = fm; pB = fm; tA = t; tB = t; }  // mom-norm lane
    else                         { int t = tile_start(6, s);  pA = fm; pB = fm; tA = t; tB = t; }  // (7,7) unused dup

    const float* aptr = pA + r * NP + tA;   // 16B-aligned by construction
    const float* bptr = pB + r * NP + tB;

    float acc[8][8];
    #pragma unroll
    for (int i = 0; i < 8; ++i)
        #pragma unroll
        for (int j = 0; j < 8; ++j) acc[i][j] = 0.0f;

    // software pipeline: prefetch next channel while FMA-ing current
    float4 a0 = *(const float4*)(aptr);
    float4 a1 = *(const float4*)(aptr + 4);
    float4 c0 = *(const float4*)(bptr);
    float4 c1 = *(const float4*)(bptr + 4);

    for (int k = 1; k < NC / 4; ++k) {
        const float* ap = aptr + k * (4 * NP);
        const float* bp = bptr + k * (4 * NP);
        float4 na0 = *(const float4*)(ap);
        float4 na1 = *(const float4*)(ap + 4);
        float4 nc0 = *(const float4*)(bp);
        float4 nc1 = *(const float4*)(bp + 4);

        float bv[8] = { a0.x, a0.y, a0.z, a0.w, a1.x, a1.y, a1.z, a1.w };
        float mv[8] = { c0.x, c0.y, c0.z, c0.w, c1.x, c1.y, c1.z, c1.w };
        #pragma unroll
        for (int i = 0; i < 8; ++i)
            #pragma unroll
            for (int j = 0; j < 8; ++j)
                acc[i][j] = fmaf(bv[i], mv[j], acc[i][j]);

        a0 = na0; a1 = na1; c0 = nc0; c1 = nc1;
    }
    {   // last channel
        float bv[8] = { a0.x, a0.y, a0.z, a0.w, a1.x, a1.y, a1.z, a1.w };
        float mv[8] = { c0.x, c0.y, c0.z, c0.w, c1.x, c1.y, c1.z, c1.w };
        #pragma unroll
        for (int i = 0; i < 8; ++i)
            #pragma unroll
            for (int j = 0; j < 8; ++j)
                acc[i][j] = fmaf(bv[i], mv[j], acc[i][j]);
    }

    // ---- combine across waves via LDS atomics (fully unrolled: no dynamic
    //      indexing into acc -> stays in VGPRs) ----
    if (lp <= 6 && lq <= 6) {
        int plo, phi, qlo, qhi;
        own_range(lp, s, plo, phi);
        own_range(lq, s, qlo, qhi);
        const int tp = tile_start(lp, s), tq = tile_start(lq, s);
        #pragma unroll
        for (int i = 0; i < 8; ++i)
            #pragma unroll
            for (int j = 0; j < 8; ++j)
                if (i >= plo && i < phi && j >= qlo && j < qhi)
                    atomicAdd(&dots[(tp + i) * NP + (tq + j)], acc[i][j]);
    } else if (lp == 7 && lq <= 6) {
        int lo, hi; own_range(lq, s, lo, hi);
        const int t = tile_start(lq, s);
        #pragma unroll
        for (int i = 0; i < 8; ++i)
            if (i >= lo && i < hi) atomicAdd(&bn[t + i], acc[i][i]);
    } else if (lq == 7 && lp <= 6) {
        int lo, hi; own_range(lp, s, lo, hi);
        const int t = tile_start(lp, s);
        #pragma unroll
        for (int i = 0; i < 8; ++i)
            if (i >= lo && i < hi) atomicAdd(&mn[t + i], acc[i][i]);
    }
    __syncthreads();

    // ---- cosine + mask + reduction over the 2401 cells ----
    float sum = 0.0f;
    for (int e = tid; e < NP * NP; e += 256) {
        int p = e / NP, q = e - p * NP;
        float w = (A1[e] == 1 ? 1.0f : 0.0f) + (A2[q * NP + p] == 1 ? 1.0f : 0.0f);
        float den = fmaxf(sqrtf(bn[p]) * sqrtf(mn[q]), EPS);
        sum += w * dots[e] / den;
    }

    #pragma unroll
    for (int m = 32; m; m >>= 1) sum += __shfl_xor(sum, m, 64);
    if (lane == 0) red[wave] = sum;
    __syncthreads();
    if (tid == 0) out[b] = (red[0] + red[1] + red[2] + red[3]) * (-1.0f / 2401.0f);
}

extern "C" void kernel_launch(void* const* d_in, const int* in_sizes, int n_in,
                              void* d_out, int out_size, void* d_ws, size_t ws_size,
                              hipStream_t stream)
{
    (void)in_sizes; (void)n_in; (void)d_ws; (void)ws_size; (void)out_size;
    const float* base = (const float*)d_in[0];
    const float* mom  = (const float*)d_in[1];
    const int*   A1   = (const int*)d_in[2];
    const int*   A2   = (const int*)d_in[3];
    float*       out  = (float*)d_out;

    pixpro_kernel<<<NBATCH, 256, 0, stream>>>(base, mom, A1, A2, out);
}